// Round 7
// baseline (1028.859 us; speedup 1.0000x reference)
//
#include <hip/hip_runtime.h>

// MS1: 64-layer reversible net, fused single-kernel recurrence.
//   Z += H*tanh(Y @ K_j^T + b_j[256:]);  Y += H*tanh(b_j[:256] - Z @ K_j)
// R7 = R6 with ONE change: amdgpu_waves_per_eu(4,4) instead of
// __launch_bounds__(1024,4). R4/R5/R6 all compiled to VGPR=64 (allocator
// shrinking to an 8-waves/EU occupancy step that LDS makes unreachable),
// which killed the depth-4 B prefetch + A ping-pong -> per-kt latency
// serialization (sum-of-pipes ~= observed 19k cyc/phase). Pinning waves/EU
// to exactly 4 gives the allocator its real 128-VGPR budget.
// Structure: 256 blocks x 32 rows, 16 waves; wave w owns n-tile w, both
// m-tiles. B global->reg depth-4 rotation; A-frag ping-pong; 6 indep MFMA
// chains; SGB-pinned interleave; one raw s_barrier per phase (vmcnt live).
// LDS = state only (64 KB). 3-pass f16 Ozaki MFMA (AhBh+AlBh+AhBl).

typedef _Float16 f16x8 __attribute__((ext_vector_type(8)));
typedef _Float16 f16x2 __attribute__((ext_vector_type(2)));
typedef float    f32x4 __attribute__((ext_vector_type(4)));

#define H_STEP 0.015625f   // 1/64

__device__ __forceinline__ float fast_tanh(float x) {
    float xc = fminf(fmaxf(x, -9.0f), 9.0f);
    float t  = __builtin_amdgcn_exp2f(xc * 2.8853900817779268f); // 2x*log2(e)
    return (t - 1.0f) * __builtin_amdgcn_rcpf(t + 1.0f);
}

// state LDS index with XOR swizzle (16B-granular column rotation per row)
__device__ __forceinline__ int swz(int m, int k) {
    return (m << 8) + (k ^ ((m & 7) << 3));
}

// ---------------- prep: K[a][b][j] -> fragment-friendly half arrays ----------
// B1[j][n][k] = K[n][k][j]  (for Y @ K^T);  B2[j][n][k] = K[k][n][j]  (Z @ K)
__global__ __launch_bounds__(256) void prep_split(
    const float* __restrict__ K,
    _Float16* __restrict__ B1h, _Float16* __restrict__ B1l,
    _Float16* __restrict__ B2h, _Float16* __restrict__ B2l)
{
    __shared__ float tile[32][33][9];
    const int a0 = (blockIdx.x & 7) << 5;
    const int b0 = ((blockIdx.x >> 3) & 7) << 5;
    const int j0 = (blockIdx.x >> 6) << 3;
    const int t = threadIdx.x;

    for (int idx = t; idx < 8192; idx += 256) {
        const int jj = idx & 7, bb = (idx >> 3) & 31, aa = idx >> 8;
        tile[aa][bb][jj] = K[((size_t)(a0 + aa) * 256 + (b0 + bb)) * 64 + (j0 + jj)];
    }
    __syncthreads();

    for (int idx = t; idx < 4096; idx += 256) {
        const int p = idx & 15, aa = (idx >> 4) & 31, jj = idx >> 9;
        const float f0 = tile[aa][2*p][jj], f1 = tile[aa][2*p+1][jj];
        const _Float16 h0 = (_Float16)f0, h1 = (_Float16)f1;
        const f16x2 hv = {h0, h1};
        const f16x2 lv = {(_Float16)(f0 - (float)h0), (_Float16)(f1 - (float)h1)};
        const size_t off = ((size_t)(j0 + jj) * 256 + (a0 + aa)) * 256 + (b0 + 2*p);
        *(f16x2*)(B1h + off) = hv;
        *(f16x2*)(B1l + off) = lv;
    }
    for (int idx = t; idx < 4096; idx += 256) {
        const int p = idx & 15, bb = (idx >> 4) & 31, jj = idx >> 9;
        const float f0 = tile[2*p][bb][jj], f1 = tile[2*p+1][bb][jj];
        const _Float16 h0 = (_Float16)f0, h1 = (_Float16)f1;
        const f16x2 hv = {h0, h1};
        const f16x2 lv = {(_Float16)(f0 - (float)h0), (_Float16)(f1 - (float)h1)};
        const size_t off = ((size_t)(j0 + jj) * 256 + (b0 + bb)) * 256 + (a0 + 2*p);
        *(f16x2*)(B2h + off) = hv;
        *(f16x2*)(B2l + off) = lv;
    }
}

#define MFMA16(A, B, C) __builtin_amdgcn_mfma_f32_16x16x32_f16((A), (B), (C), 0, 0, 0)
#define SGB(MASK, N) __builtin_amdgcn_sched_group_barrier((MASK), (N), 0)
// masks: MFMA=0x8, VMEM_READ=0x20, DS_READ=0x100

// read one kt's A fragments (both m-tiles, hi+lo) from state LDS
#define LOAD_A(DH0, DL0, DH1, DL1, PK)                                          \
    {                                                                           \
        const int k0_ = (PK) * 32 + hi4 * 8;                                    \
        DH0 = *(const f16x8*)(lds + stA + swz(l15, k0_));                       \
        DL0 = *(const f16x8*)(lds + stA + 8192 + swz(l15, k0_));                \
        DH1 = *(const f16x8*)(lds + stA + swz(16 + l15, k0_));                  \
        DL1 = *(const f16x8*)(lds + stA + 8192 + swz(16 + l15, k0_));           \
    }

// one kt: consume B slot, refill it for kt+4, prefetch next A, 6 indep MFMAs.
// sched_group_barrier sequence pins the per-kt interleave:
//   1 MFMA | 1 VMEM | 2 DS | 2 MFMA | 1 VMEM | 2 DS | 3 MFMA
#define KT(VKT, SH, SL, CH0, CL0, CH1, CL1, NH0, NL0, NH1, NL1)                 \
    {                                                                           \
        const f16x8 bh = SH, bl = SL;                                           \
        {                                                                       \
            const int pkp_ = (((VKT) + 4) & 7) * 32;                            \
            const _Float16* ph_ = ((VKT) <= 3) ? Bh : BhN;                      \
            const _Float16* pl_ = ((VKT) <= 3) ? Bl : BlN;                      \
            SH = *(const f16x8*)(ph_ + boff + pkp_);                            \
            SL = *(const f16x8*)(pl_ + boff + pkp_);                            \
        }                                                                       \
        if ((VKT) < 7) LOAD_A(NH0, NL0, NH1, NL1, (VKT) + 1)                    \
        accH0 = MFMA16(CH0, bh, accH0);                                         \
        accH1 = MFMA16(CH1, bh, accH1);                                         \
        accM0 = MFMA16(CL0, bh, accM0);                                         \
        accM1 = MFMA16(CL1, bh, accM1);                                         \
        accL0 = MFMA16(CH0, bl, accL0);                                         \
        accL1 = MFMA16(CH1, bl, accL1);                                         \
        if ((VKT) < 7) {                                                        \
            SGB(0x8, 1); SGB(0x20, 1); SGB(0x100, 2); SGB(0x8, 2);              \
            SGB(0x20, 1); SGB(0x100, 2); SGB(0x8, 3);                           \
        } else {                                                                \
            SGB(0x8, 3); SGB(0x20, 2); SGB(0x8, 3);                             \
        }                                                                       \
    }

// one half-layer: 8 k-tiles + epilogue + single raw barrier
template<bool NEG>
__device__ __forceinline__ void phase(
    _Float16* lds, const int stA, const int stO,
    const _Float16* __restrict__ Bh,  const _Float16* __restrict__ Bl,
    const _Float16* __restrict__ BhN, const _Float16* __restrict__ BlN,
    const float* __restrict__ bias,      // pre-offset: bvec + featbase*64 + j
    float (&M)[2][4],
    f16x8& s0h, f16x8& s0l, f16x8& s1h, f16x8& s1l,
    f16x8& s2h, f16x8& s2l, f16x8& s3h, f16x8& s3l,
    const int boff, const int n, const int l15, const int hi4)
{
    const float bv = bias[(size_t)n * 64];

    f32x4 accH0 = {0.f,0.f,0.f,0.f}, accH1 = {0.f,0.f,0.f,0.f};
    f32x4 accM0 = {0.f,0.f,0.f,0.f}, accM1 = {0.f,0.f,0.f,0.f};
    f32x4 accL0 = {0.f,0.f,0.f,0.f}, accL1 = {0.f,0.f,0.f,0.f};

    f16x8 cH0, cL0, cH1, cL1, nH0, nL0, nH1, nL1;
    LOAD_A(cH0, cL0, cH1, cL1, 0)

    KT(0, s0h, s0l, cH0, cL0, cH1, cL1, nH0, nL0, nH1, nL1)
    KT(1, s1h, s1l, nH0, nL0, nH1, nL1, cH0, cL0, cH1, cL1)
    KT(2, s2h, s2l, cH0, cL0, cH1, cL1, nH0, nL0, nH1, nL1)
    KT(3, s3h, s3l, nH0, nL0, nH1, nL1, cH0, cL0, cH1, cL1)
    KT(4, s0h, s0l, cH0, cL0, cH1, cL1, nH0, nL0, nH1, nL1)
    KT(5, s1h, s1l, nH0, nL0, nH1, nL1, cH0, cL0, cH1, cL1)
    KT(6, s2h, s2l, cH0, cL0, cH1, cL1, nH0, nL0, nH1, nL1)
    KT(7, s3h, s3l, nH0, nL0, nH1, nL1, cH0, cL0, cH1, cL1)

    // epilogue: sum chains, master += H*tanh(bias +/- acc), re-split to LDS
#pragma unroll
    for (int mt = 0; mt < 2; ++mt) {
        const f32x4 a4 = mt ? ((accH1 + accM1) + accL1)
                            : ((accH0 + accM0) + accL0);
#pragma unroll
        for (int q = 0; q < 4; ++q) {
            const float x = NEG ? (bv - a4[q]) : (a4[q] + bv);
            const float v = M[mt][q] + H_STEP * fast_tanh(x);
            M[mt][q] = v;
            const _Float16 vh = (_Float16)v;
            const int m = mt * 16 + hi4 * 4 + q;
            const int o = swz(m, n);
            lds[stO + o] = vh;
            lds[stO + 8192 + o] = (_Float16)(v - (float)vh);
        }
    }
    // my LDS ops complete -> signal; raw barrier (vmcnt loads stay in flight)
    asm volatile("s_waitcnt lgkmcnt(0)" ::: "memory");
    __builtin_amdgcn_s_barrier();
    __builtin_amdgcn_sched_barrier(0);
}

__global__
__attribute__((amdgpu_flat_work_group_size(1024, 1024), amdgpu_waves_per_eu(4, 4)))
void ms1_main(
    const float* __restrict__ Y0,
    const float* __restrict__ bvec,
    const _Float16* __restrict__ B1h, const _Float16* __restrict__ B1l,
    const _Float16* __restrict__ B2h, const _Float16* __restrict__ B2l,
    float* __restrict__ out)
{
    // state only: Y hi/lo @0/8192, Z hi/lo @16384/24576  (64 KB)
    __shared__ _Float16 lds[32768];
#define ST_Y 0
#define ST_Z 16384

    const int tid  = threadIdx.x;
    const int lane = tid & 63, w = tid >> 6;   // 16 waves = 16 n-tiles
    const int l15 = lane & 15, hi4 = lane >> 4;
    const int n    = w * 16 + l15;             // this lane's output column
    const int boff = n * 256 + hi4 * 8;        // B fragment base (halfs)
    const size_t row0 = (size_t)blockIdx.x * 32;

    float Ym[2][4], Zm[2][4];                  // fp32 masters [mt][q]

#pragma unroll
    for (int mt = 0; mt < 2; ++mt) {
#pragma unroll
        for (int q = 0; q < 4; ++q) {
            const int m = mt * 16 + hi4 * 4 + q;
            const size_t base = (row0 + m) * 512;
            const float y = Y0[base + n];
            const float z = Y0[base + 256 + n];
            Ym[mt][q] = y; Zm[mt][q] = z;
            const _Float16 yh = (_Float16)y;
            const int o = swz(m, n);
            lds[ST_Y + o] = yh;
            lds[ST_Y + 8192 + o] = (_Float16)(y - (float)yh);
        }
    }
    __syncthreads();

    // prologue: prefetch phase-0 k-tiles 0..3 into the 4 rotating slots
    f16x8 s0h = *(const f16x8*)(B1h + boff);
    f16x8 s0l = *(const f16x8*)(B1l + boff);
    f16x8 s1h = *(const f16x8*)(B1h + boff + 32);
    f16x8 s1l = *(const f16x8*)(B1l + boff + 32);
    f16x8 s2h = *(const f16x8*)(B1h + boff + 64);
    f16x8 s2l = *(const f16x8*)(B1l + boff + 64);
    f16x8 s3h = *(const f16x8*)(B1h + boff + 96);
    f16x8 s3l = *(const f16x8*)(B1l + boff + 96);

    for (int j = 0; j < 64; ++j) {
        const size_t jb  = (size_t)j << 16;
        const size_t jbn = (j < 63) ? ((size_t)(j + 1) << 16) : 0; // wrap: dead
        // Z += H*tanh(Y @ K^T + b[256:])   (A=Y; next-phase B = B2 of same j)
        phase<false>(lds, ST_Y, ST_Z, B1h + jb, B1l + jb, B2h + jb, B2l + jb,
                     bvec + 256 * 64 + j, Zm,
                     s0h, s0l, s1h, s1l, s2h, s2l, s3h, s3l,
                     boff, n, l15, hi4);
        // Y += H*tanh(b[:256] - Z @ K)     (A=Z; next-phase B = B1 of j+1)
        phase<true>(lds, ST_Z, ST_Y, B2h + jb, B2l + jb, B1h + jbn, B1l + jbn,
                    bvec + j, Ym,
                    s0h, s0l, s1h, s1l, s2h, s2l, s3h, s3l,
                    boff, n, l15, hi4);
    }

#pragma unroll
    for (int mt = 0; mt < 2; ++mt) {
#pragma unroll
        for (int q = 0; q < 4; ++q) {
            const int m = mt * 16 + hi4 * 4 + q;
            const size_t base = (row0 + m) * 512;
            out[base + n]       = Ym[mt][q];
            out[base + 256 + n] = Zm[mt][q];
        }
    }
}

extern "C" void kernel_launch(void* const* d_in, const int* in_sizes, int n_in,
                              void* d_out, int out_size, void* d_ws, size_t ws_size,
                              hipStream_t stream) {
    (void)in_sizes; (void)n_in; (void)out_size;
    const float* Y0 = (const float*)d_in[0];
    const float* K  = (const float*)d_in[1];
    const float* b  = (const float*)d_in[2];

    const size_t ARR = (size_t)64 * 256 * 256;
    if (ws_size < 4 * ARR * sizeof(_Float16)) return;

    _Float16* B1h = (_Float16*)d_ws;
    _Float16* B1l = B1h + ARR;
    _Float16* B2h = B1l + ARR;
    _Float16* B2l = B2h + ARR;

    prep_split<<<512, 256, 0, stream>>>(K, B1h, B1l, B2h, B2l);
    ms1_main<<<256, 1024, 0, stream>>>(Y0, b, B1h, B1l, B2h, B2l, (float*)d_out);
}

// Round 8
// 573.787 us; speedup vs baseline: 1.7931x; 1.7931x over previous
//
#include <hip/hip_runtime.h>

// MS1: 64-layer reversible net, fused single-kernel recurrence.
//   Z += H*tanh(Y @ K_j^T + b_j[256:]);  Y += H*tanh(b_j[:256] - Z @ K_j)
// R8: B staging via global_load_lds DMA (no VGPR round-trip, cannot be
// sunk by the scheduler - fixes R4-R7's dead prefetch) into 3 rotating
// 32KB LDS k-tile buffers, ordered by per-wave counted s_waitcnt vmcnt(5).
// KEY: staging is WAVE-LOCAL (thread t stages exactly the bytes wave w=t/64
// reads) -> zero barriers in the B pipeline; one raw s_barrier per phase
// (state handoff only). LDS = 64KB state + 96KB B = 160KB.
// 256 blocks x 32 rows, 1024 threads (16 waves); wave w owns n-tile w, both
// m-tiles; 6 independent MFMA chains; 3-pass f16 Ozaki (AhBh+AlBh+AhBl).

typedef _Float16 f16x8 __attribute__((ext_vector_type(8)));
typedef _Float16 f16x2 __attribute__((ext_vector_type(2)));
typedef float    f32x4 __attribute__((ext_vector_type(4)));

#define H_STEP 0.015625f   // 1/64

// LDS layout in halfs: Y hi/lo @0/8192, Z hi/lo @16384/24576,
// B tile buffers i=0..2 @ 32768+i*16384 (hi at +0, lo at +8192 within tile)
#define ST_Y  0
#define ST_Z  16384
#define BUF0  32768
#define BUFSZ 16384

__device__ __forceinline__ float fast_tanh(float x) {
    float xc = fminf(fmaxf(x, -9.0f), 9.0f);
    float t  = __builtin_amdgcn_exp2f(xc * 2.8853900817779268f); // 2x*log2(e)
    return (t - 1.0f) * __builtin_amdgcn_rcpf(t + 1.0f);
}

// state LDS index with XOR swizzle (16B-granular column rotation per row)
__device__ __forceinline__ int swz(int m, int k) {
    return (m << 8) + (k ^ ((m & 7) << 3));
}

// 16B global -> LDS direct DMA (dest must be wave-uniform base; lane*16 added by HW)
__device__ __forceinline__ void gload16(const _Float16* g, _Float16* l) {
    __builtin_amdgcn_global_load_lds(
        (const __attribute__((address_space(1))) unsigned int*)g,
        (__attribute__((address_space(3))) unsigned int*)l, 16, 0, 0);
}

// ---------------- prep: K[a][b][j] -> DMA-tile-ordered half arrays ----------
// Arrays: [j][kt][unit u of 16B]: u = n*4 + (c ^ ((n>>1)&3)), unit holds
// B[n][k = kt*32 + c*8 .. +8].  B1[n][k]=K[n][k][j] (Y@K^T);  B2[n][k]=K[k][n][j] (Z@K)
__global__ __launch_bounds__(256) void prep_split(
    const float* __restrict__ K,
    _Float16* __restrict__ B1h, _Float16* __restrict__ B1l,
    _Float16* __restrict__ B2h, _Float16* __restrict__ B2l)
{
    __shared__ float tile[32][33][9];
    const int a0 = (blockIdx.x & 7) << 5;
    const int b0 = ((blockIdx.x >> 3) & 7) << 5;
    const int j0 = (blockIdx.x >> 6) << 3;
    const int t = threadIdx.x;

    for (int idx = t; idx < 8192; idx += 256) {
        const int jj = idx & 7, bb = (idx >> 3) & 31, aa = idx >> 8;
        tile[aa][bb][jj] = K[((size_t)(a0 + aa) * 256 + (b0 + bb)) * 64 + (j0 + jj)];
    }
    __syncthreads();

    // B1: n = a0+aa, k = b0+kl  (kt = b0>>5)
    {
        const int kt = b0 >> 5;
        for (int idx = t; idx < 4096; idx += 256) {
            const int p = idx & 15, aa = (idx >> 4) & 31, jj = idx >> 9;
            const int n = a0 + aa, kl = 2 * p, c = kl >> 3, e = kl & 7;
            const float f0 = tile[aa][kl][jj], f1 = tile[aa][kl + 1][jj];
            const _Float16 h0 = (_Float16)f0, h1 = (_Float16)f1;
            const f16x2 hv = {h0, h1};
            const f16x2 lv = {(_Float16)(f0 - (float)h0), (_Float16)(f1 - (float)h1)};
            const size_t off = ((size_t)(j0 + jj) * 8 + kt) * 8192
                             + (size_t)(n * 4 + (c ^ ((n >> 1) & 3))) * 8 + e;
            *(f16x2*)(B1h + off) = hv;
            *(f16x2*)(B1l + off) = lv;
        }
    }
    // B2: n = b0+bb, k = a0+kl  (kt = a0>>5)
    {
        const int kt = a0 >> 5;
        for (int idx = t; idx < 4096; idx += 256) {
            const int p = idx & 15, bb = (idx >> 4) & 31, jj = idx >> 9;
            const int n = b0 + bb, kl = 2 * p, c = kl >> 3, e = kl & 7;
            const float f0 = tile[kl][bb][jj], f1 = tile[kl + 1][bb][jj];
            const _Float16 h0 = (_Float16)f0, h1 = (_Float16)f1;
            const f16x2 hv = {h0, h1};
            const f16x2 lv = {(_Float16)(f0 - (float)h0), (_Float16)(f1 - (float)h1)};
            const size_t off = ((size_t)(j0 + jj) * 8 + kt) * 8192
                             + (size_t)(n * 4 + (c ^ ((n >> 1) & 3))) * 8 + e;
            *(f16x2*)(B2h + off) = hv;
            *(f16x2*)(B2l + off) = lv;
        }
    }
}

#define MFMA16(A, B, C) __builtin_amdgcn_mfma_f32_16x16x32_f16((A), (B), (C), 0, 0, 0)

// one half-layer: 8 k-tiles (DMA-pipelined, wave-local sync) + epilogue + barrier
template<bool NEG>
__device__ __forceinline__ void phase(
    _Float16* lds, const int stA, const int stO,
    const _Float16* __restrict__ srcCh, const _Float16* __restrict__ srcCl,  // cur j-block
    const _Float16* __restrict__ srcNh, const _Float16* __restrict__ srcNl,  // next phase j-block
    const float* __restrict__ bias,      // pre-offset: bvec + featbase*64 + j
    float (&M)[2][4],
    const int ph3, const int u8, const int t8, const int w512,
    const int n, const int l15, const int hi4)
{
    const float bv = bias[(size_t)n * 64];

    f32x4 accH0 = {0.f,0.f,0.f,0.f}, accH1 = {0.f,0.f,0.f,0.f};
    f32x4 accM0 = {0.f,0.f,0.f,0.f}, accM1 = {0.f,0.f,0.f,0.f};
    f32x4 accL0 = {0.f,0.f,0.f,0.f}, accL1 = {0.f,0.f,0.f,0.f};

#pragma unroll
    for (int kt = 0; kt < 8; ++kt) {
        int bufc = ph3 + (kt % 3); if (bufc >= 3) bufc -= 3;   // (Tb+kt)%3
        const int bb = BUF0 + bufc * BUFSZ;

        // my tile's 2 DMA ops (issued 3 tiles ago) retired when <=4 DMA (+1 bias) remain
        asm volatile("s_waitcnt vmcnt(5)" ::: "memory");
        __builtin_amdgcn_sched_barrier(0);

        const f16x8 bh  = *(const f16x8*)(lds + bb + u8);
        const f16x8 bl  = *(const f16x8*)(lds + bb + 8192 + u8);
        const int k0 = kt * 32 + hi4 * 8;
        const f16x8 ah0 = *(const f16x8*)(lds + stA + swz(l15, k0));
        const f16x8 al0 = *(const f16x8*)(lds + stA + 8192 + swz(l15, k0));
        const f16x8 ah1 = *(const f16x8*)(lds + stA + swz(16 + l15, k0));
        const f16x8 al1 = *(const f16x8*)(lds + stA + 8192 + swz(16 + l15, k0));

        // frags in regs before the DMA below overwrites this buffer
        asm volatile("s_waitcnt lgkmcnt(0)" ::: "memory");
        __builtin_amdgcn_sched_barrier(0);

        // refill this buffer with tile T+3 (same buf mod 3); wave-local, no barrier
        if (kt < 5) {
            gload16(srcCh + (kt + 3) * 8192 + t8, lds + bb + w512);
            gload16(srcCl + (kt + 3) * 8192 + t8, lds + bb + 8192 + w512);
        } else {
            gload16(srcNh + (kt - 5) * 8192 + t8, lds + bb + w512);
            gload16(srcNl + (kt - 5) * 8192 + t8, lds + bb + 8192 + w512);
        }

        accH0 = MFMA16(ah0, bh, accH0);
        accH1 = MFMA16(ah1, bh, accH1);
        accM0 = MFMA16(al0, bh, accM0);
        accM1 = MFMA16(al1, bh, accM1);
        accL0 = MFMA16(ah0, bl, accL0);
        accL1 = MFMA16(ah1, bl, accL1);
    }

    // epilogue: sum chains, master += H*tanh(bias +/- acc), re-split to LDS
#pragma unroll
    for (int mt = 0; mt < 2; ++mt) {
        const f32x4 a4 = mt ? ((accH1 + accM1) + accL1)
                            : ((accH0 + accM0) + accL0);
#pragma unroll
        for (int q = 0; q < 4; ++q) {
            const float x = NEG ? (bv - a4[q]) : (a4[q] + bv);
            const float v = M[mt][q] + H_STEP * fast_tanh(x);
            M[mt][q] = v;
            const _Float16 vh = (_Float16)v;
            const int m = mt * 16 + hi4 * 4 + q;
            const int o = swz(m, n);
            lds[stO + o] = vh;
            lds[stO + 8192 + o] = (_Float16)(v - (float)vh);
        }
    }
    // state writes visible -> raw barrier (DMA vmcnt stays live across it)
    asm volatile("s_waitcnt lgkmcnt(0)" ::: "memory");
    __builtin_amdgcn_s_barrier();
    __builtin_amdgcn_sched_barrier(0);
}

__global__ __launch_bounds__(1024, 4) void ms1_main(
    const float* __restrict__ Y0,
    const float* __restrict__ bvec,
    const _Float16* __restrict__ B1h, const _Float16* __restrict__ B1l,
    const _Float16* __restrict__ B2h, const _Float16* __restrict__ B2l,
    float* __restrict__ out)
{
    extern __shared__ _Float16 lds[];   // 81920 halfs = 160 KB

    const int tid  = threadIdx.x;
    const int lane = tid & 63, w = tid >> 6;   // 16 waves = 16 n-tiles
    const int l15 = lane & 15, hi4 = lane >> 4;
    const int n    = w * 16 + l15;                       // output column
    const int u8   = (n * 4 + (hi4 ^ ((n >> 1) & 3))) * 8; // B frag offset (halfs)
    const int t8   = tid * 8;                            // DMA source offset (halfs)
    const int w512 = w * 512;                            // DMA dest wave base (halfs)
    const size_t row0 = (size_t)blockIdx.x * 32;

    float Ym[2][4], Zm[2][4];                  // fp32 masters [mt][q]

#pragma unroll
    for (int mt = 0; mt < 2; ++mt) {
#pragma unroll
        for (int q = 0; q < 4; ++q) {
            const int m = mt * 16 + hi4 * 4 + q;
            const size_t base = (row0 + m) * 512;
            const float y = Y0[base + n];
            const float z = Y0[base + 256 + n];
            Ym[mt][q] = y; Zm[mt][q] = z;
            const _Float16 yh = (_Float16)y;
            const int o = swz(m, n);
            lds[ST_Y + o] = yh;
            lds[ST_Y + 8192 + o] = (_Float16)(y - (float)yh);
        }
    }
    __syncthreads();   // init only (drains everything; no DMAs in flight yet)

    // prologue: DMA tiles 0,1,2 of (j=0, B1) into bufs 0,1,2
    gload16(B1h + 0 * 8192 + t8, lds + BUF0 + 0 * BUFSZ + w512);
    gload16(B1l + 0 * 8192 + t8, lds + BUF0 + 0 * BUFSZ + 8192 + w512);
    gload16(B1h + 1 * 8192 + t8, lds + BUF0 + 1 * BUFSZ + w512);
    gload16(B1l + 1 * 8192 + t8, lds + BUF0 + 1 * BUFSZ + 8192 + w512);
    gload16(B1h + 2 * 8192 + t8, lds + BUF0 + 2 * BUFSZ + w512);
    gload16(B1l + 2 * 8192 + t8, lds + BUF0 + 2 * BUFSZ + 8192 + w512);

    int ph3 = 0;   // (tile base) mod 3, advances by 8%3=2 per phase
    for (int j = 0; j < 64; ++j) {
        const _Float16* C1h = B1h + (size_t)j * 65536;
        const _Float16* C1l = B1l + (size_t)j * 65536;
        const _Float16* C2h = B2h + (size_t)j * 65536;
        const _Float16* C2l = B2l + (size_t)j * 65536;
        // Z += H*tanh(Y @ K^T + b[256:])   (A=Y; next-phase B = B2 of same j)
        phase<false>(lds, ST_Y, ST_Z, C1h, C1l, C2h, C2l,
                     bvec + 256 * 64 + j, Zm, ph3, u8, t8, w512, n, l15, hi4);
        ph3 += 2; if (ph3 >= 3) ph3 -= 3;
        // Y += H*tanh(b[:256] - Z @ K)     (A=Z; next-phase B = B1 of j+1)
        const int jn = (j < 63) ? j + 1 : 0;   // wrap: dead prefetch, in-bounds
        phase<true>(lds, ST_Z, ST_Y, C2h, C2l,
                    B1h + (size_t)jn * 65536, B1l + (size_t)jn * 65536,
                    bvec + j, Ym, ph3, u8, t8, w512, n, l15, hi4);
        ph3 += 2; if (ph3 >= 3) ph3 -= 3;
    }

#pragma unroll
    for (int mt = 0; mt < 2; ++mt) {
#pragma unroll
        for (int q = 0; q < 4; ++q) {
            const int m = mt * 16 + hi4 * 4 + q;
            const size_t base = (row0 + m) * 512;
            out[base + n]       = Ym[mt][q];
            out[base + 256 + n] = Zm[mt][q];
        }
    }
}

extern "C" void kernel_launch(void* const* d_in, const int* in_sizes, int n_in,
                              void* d_out, int out_size, void* d_ws, size_t ws_size,
                              hipStream_t stream) {
    (void)in_sizes; (void)n_in; (void)out_size;
    const float* Y0 = (const float*)d_in[0];
    const float* K  = (const float*)d_in[1];
    const float* b  = (const float*)d_in[2];

    const size_t ARR = (size_t)64 * 256 * 256;
    if (ws_size < 4 * ARR * sizeof(_Float16)) return;

    _Float16* B1h = (_Float16*)d_ws;
    _Float16* B1l = B1h + ARR;
    _Float16* B2h = B1l + ARR;
    _Float16* B2l = B2h + ARR;

    hipFuncSetAttribute((const void*)ms1_main,
                        hipFuncAttributeMaxDynamicSharedMemorySize, 163840);

    prep_split<<<512, 256, 0, stream>>>(K, B1h, B1l, B2h, B2l);
    ms1_main<<<256, 1024, 163840, stream>>>(Y0, b, B1h, B1l, B2h, B2l, (float*)d_out);
}

// Round 9
// 380.294 us; speedup vs baseline: 2.7054x; 1.5088x over previous
//
#include <hip/hip_runtime.h>

// MS1: 64-layer reversible net, fused single-kernel recurrence.
//   Z += H*tanh(Y @ K_j^T + b_j[256:]);  Y += H*tanh(b_j[:256] - Z @ K_j)
// R9: LDS-traffic reduction. 512 threads (8 waves), wave w owns BOTH m-tiles
// x 2 n-tiles (cols 32w..32w+31) -> A-state read 8x (was 16x). 2-pass Ozaki
// D=(Ah+Al)*Bh (B fp16-rounded, hi only): halves B volume + 8 MFMAs/kt.
// B staged via wave-local global_load_lds DMA into 4 rotating 16KB buffers,
// exact counted vmcnt; bias DMA'd per-lane-gather into LDS (exact counts).
// ds_read prefetch one kt ahead; one raw s_barrier per phase. LDS ~130KB.

typedef _Float16 f16x8 __attribute__((ext_vector_type(8)));
typedef _Float16 f16x2 __attribute__((ext_vector_type(2)));
typedef float    f32x4 __attribute__((ext_vector_type(4)));

#define H_STEP 0.015625f   // 1/64

// LDS layout in halfs:
#define ST_Y   0          // Y: hi 0..8191, lo 8192..16383
#define ST_Z   16384      // Z: hi, lo
#define BUF0   32768      // 4 buffers x 8192 halfs (16KB each)
#define BIASO  65536      // 8 waves x 64 f32 = 1024 halfs
// total 66560 halfs = 133120 bytes

__device__ __forceinline__ float fast_tanh(float x) {
    float xc = fminf(fmaxf(x, -9.0f), 9.0f);
    float t  = __builtin_amdgcn_exp2f(xc * 2.8853900817779268f); // 2x*log2(e)
    return (t - 1.0f) * __builtin_amdgcn_rcpf(t + 1.0f);
}

// state LDS index with XOR swizzle (16B-granular column rotation per row)
__device__ __forceinline__ int swz(int m, int k) {
    return (m << 8) + (k ^ ((m & 7) << 3));
}

__device__ __forceinline__ void gload16(const _Float16* g, _Float16* l) {
    __builtin_amdgcn_global_load_lds(
        (const __attribute__((address_space(1))) unsigned int*)g,
        (__attribute__((address_space(3))) unsigned int*)l, 16, 0, 0);
}
__device__ __forceinline__ void gload4(const float* g, _Float16* l) {
    __builtin_amdgcn_global_load_lds(
        (const __attribute__((address_space(1))) unsigned int*)g,
        (__attribute__((address_space(3))) unsigned int*)l, 4, 0, 0);
}

// ---------------- prep: K[a][b][j] -> DMA-tile-ordered fp16 arrays ----------
// Layout: [j][kt][w 0..7][u 0..127][8 halfs]; unit u = c_local*4 + (chunk ^
// ((c_local>>1)&3)) holds B[col=32w+c_local][k=kt*32+chunk*8 ..+8].
// B1[n][k]=K[n][k][j] (Y@K^T);  B2[n][k]=K[k][n][j] (Z@K)
__global__ __launch_bounds__(256) void prep_split(
    const float* __restrict__ K,
    _Float16* __restrict__ B1h, _Float16* __restrict__ B2h)
{
    __shared__ float tile[32][33][9];
    const int a0 = (blockIdx.x & 7) << 5;
    const int b0 = ((blockIdx.x >> 3) & 7) << 5;
    const int j0 = (blockIdx.x >> 6) << 3;
    const int t = threadIdx.x;

    for (int idx = t; idx < 8192; idx += 256) {
        const int jj = idx & 7, bb = (idx >> 3) & 31, aa = idx >> 8;
        tile[aa][bb][jj] = K[((size_t)(a0 + aa) * 256 + (b0 + bb)) * 64 + (j0 + jj)];
    }
    __syncthreads();

    // B1: n = a0+aa (w1=a0>>5, c_local=aa), k = b0+kl (kt=b0>>5)
    {
        const int w1 = a0 >> 5, kt = b0 >> 5;
        for (int idx = t; idx < 4096; idx += 256) {
            const int p = idx & 15, aa = (idx >> 4) & 31, jj = idx >> 9;
            const int kl = 2 * p, c = kl >> 3, e = kl & 7;
            const int u = aa * 4 + (c ^ ((aa >> 1) & 3));
            const size_t off = ((size_t)((j0 + jj) * 8 + kt)) * 8192 + w1 * 1024 + u * 8 + e;
            const f16x2 hv = {(_Float16)tile[aa][kl][jj], (_Float16)tile[aa][kl + 1][jj]};
            *(f16x2*)(B1h + off) = hv;
        }
    }
    // B2: n = b0+bb (w2=b0>>5, c_local=bb), k = a0+kl (kt=a0>>5)
    {
        const int w2 = b0 >> 5, kt = a0 >> 5;
        for (int idx = t; idx < 4096; idx += 256) {
            const int p = idx & 15, bb = (idx >> 4) & 31, jj = idx >> 9;
            const int kl = 2 * p, c = kl >> 3, e = kl & 7;
            const int u = bb * 4 + (c ^ ((bb >> 1) & 3));
            const size_t off = ((size_t)((j0 + jj) * 8 + kt)) * 8192 + w2 * 1024 + u * 8 + e;
            const f16x2 hv = {(_Float16)tile[kl][bb][jj], (_Float16)tile[kl + 1][bb][jj]};
            *(f16x2*)(B2h + off) = hv;
        }
    }
}

#define MFMA16(A, B, C) __builtin_amdgcn_mfma_f32_16x16x32_f16((A), (B), (C), 0, 0, 0)
#define SBAR __builtin_amdgcn_sched_barrier(0)

// issue the 6 ds_reads for k-tile PK into the given regs
#define LOAD_FRAGS(AH0, AL0, AH1, AL1, BH0, BH1, PK)                            \
    {                                                                           \
        const int k0_ = (PK) * 32 + hi4 * 8;                                    \
        const _Float16* bb_ = lds + BUF0 + ((PK) & 3) * 8192 + bfw;             \
        BH0 = *(const f16x8*)(bb_ + bf0);                                       \
        BH1 = *(const f16x8*)(bb_ + bf1);                                       \
        AH0 = *(const f16x8*)(lds + stA + swz(l15, k0_));                       \
        AL0 = *(const f16x8*)(lds + stA + 8192 + swz(l15, k0_));                \
        AH1 = *(const f16x8*)(lds + stA + swz(16 + l15, k0_));                  \
        AL1 = *(const f16x8*)(lds + stA + 8192 + swz(16 + l15, k0_));           \
    }

// one k-tile. VM = exact vmcnt so tile VKT+1 is fully in LDS before its reads.
// Order: [vmcnt][lgkm0: my kt-reads done, buf VKT&3 free][DMA T_{VKT+4} into
// buf VKT&3][issue reads R_{VKT+1}][8 MFMAs on CUR regs].
#define KT(VKT, VM, CAH0,CAL0,CAH1,CAL1,CBH0,CBH1, NAH0,NAL0,NAH1,NAL1,NBH0,NBH1) \
    {                                                                           \
        if ((VKT) < 7) { asm volatile("s_waitcnt vmcnt(" #VM ")" ::: "memory"); SBAR; } \
        asm volatile("s_waitcnt lgkmcnt(0)" ::: "memory"); SBAR;                \
        {                                                                       \
            const _Float16* sb_ = ((VKT) < 4) ? Bc : Bn;                        \
            const int tt_ = ((VKT) + 4) & 7;                                    \
            _Float16* db_ = lds + BUF0 + ((VKT) & 3) * 8192 + gdst;             \
            gload16(sb_ + tt_ * 8192 + gsrc,       db_);                        \
            gload16(sb_ + tt_ * 8192 + gsrc + 512, db_ + 512);                  \
        }                                                                       \
        if ((VKT) == 0) gload4(biasG + bsrc, lds + BIASO + (w << 7));           \
        if ((VKT) < 7) LOAD_FRAGS(NAH0, NAL0, NAH1, NAL1, NBH0, NBH1, (VKT) + 1)\
        accH00 = MFMA16(CAH0, CBH0, accH00);                                    \
        accH01 = MFMA16(CAH0, CBH1, accH01);                                    \
        accH10 = MFMA16(CAH1, CBH0, accH10);                                    \
        accH11 = MFMA16(CAH1, CBH1, accH11);                                    \
        accL00 = MFMA16(CAL0, CBH0, accL00);                                    \
        accL01 = MFMA16(CAL0, CBH1, accL01);                                    \
        accL10 = MFMA16(CAL1, CBH0, accL10);                                    \
        accL11 = MFMA16(CAL1, CBH1, accL11);                                    \
    }

// one half-layer: 8 pipelined k-tiles + epilogue + single raw barrier
template<bool NEG>
__device__ __forceinline__ void phase(
    _Float16* lds, const int stA, const int stO,
    const _Float16* __restrict__ Bc,   // this half-layer's B array (j base)
    const _Float16* __restrict__ Bn,   // next half-layer's B array
    const float* __restrict__ biasG,   // bvec + featbase*64 + j
    float (&M)[2][2][4],
    const int w, const int l15, const int hi4,
    const int bfw, const int bf0, const int bf1,
    const int gsrc, const int gdst, const size_t bsrc)
{
    f32x4 accH00 = {0.f,0.f,0.f,0.f}, accH01 = {0.f,0.f,0.f,0.f};
    f32x4 accH10 = {0.f,0.f,0.f,0.f}, accH11 = {0.f,0.f,0.f,0.f};
    f32x4 accL00 = {0.f,0.f,0.f,0.f}, accL01 = {0.f,0.f,0.f,0.f};
    f32x4 accL10 = {0.f,0.f,0.f,0.f}, accL11 = {0.f,0.f,0.f,0.f};

    f16x8 cah0, cal0, cah1, cal1, cbh0, cbh1;
    f16x8 nah0, nal0, nah1, nal1, nbh0, nbh1;

    // pre-loop: T0 resident (outstanding T1,T2,T3 = 6), read k-tile 0
    asm volatile("s_waitcnt vmcnt(6)" ::: "memory"); SBAR;
    LOAD_FRAGS(cah0, cal0, cah1, cal1, cbh0, cbh1, 0)

    KT(0, 4, cah0,cal0,cah1,cal1,cbh0,cbh1, nah0,nal0,nah1,nal1,nbh0,nbh1)
    KT(1, 5, nah0,nal0,nah1,nal1,nbh0,nbh1, cah0,cal0,cah1,cal1,cbh0,cbh1)
    KT(2, 5, cah0,cal0,cah1,cal1,cbh0,cbh1, nah0,nal0,nah1,nal1,nbh0,nbh1)
    KT(3, 5, nah0,nal0,nah1,nal1,nbh0,nbh1, cah0,cal0,cah1,cal1,cbh0,cbh1)
    KT(4, 4, cah0,cal0,cah1,cal1,cbh0,cbh1, nah0,nal0,nah1,nal1,nbh0,nbh1)
    KT(5, 4, nah0,nal0,nah1,nal1,nbh0,nbh1, cah0,cal0,cah1,cal1,cbh0,cbh1)
    KT(6, 4, cah0,cal0,cah1,cal1,cbh0,cbh1, nah0,nal0,nah1,nal1,nbh0,nbh1)
    KT(7, 0, nah0,nal0,nah1,nal1,nbh0,nbh1, cah0,cal0,cah1,cal1,cbh0,cbh1)

    // epilogue: bias from LDS, master += H*tanh(bias +/- acc), re-split state
    const float* bp = (const float*)(lds + BIASO + (w << 7));
    const float bv0 = bp[l15], bv1 = bp[l15 + 16];

#pragma unroll
    for (int mt = 0; mt < 2; ++mt) {
#pragma unroll
        for (int nt = 0; nt < 2; ++nt) {
            const f32x4 s4 = (mt == 0)
                ? ((nt == 0) ? (accH00 + accL00) : (accH01 + accL01))
                : ((nt == 0) ? (accH10 + accL10) : (accH11 + accL11));
            const float bv = nt ? bv1 : bv0;
            const int n = (w << 5) + nt * 16 + l15;
#pragma unroll
            for (int q = 0; q < 4; ++q) {
                const float x = NEG ? (bv - s4[q]) : (s4[q] + bv);
                const float v = M[mt][nt][q] + H_STEP * fast_tanh(x);
                M[mt][nt][q] = v;
                const _Float16 vh = (_Float16)v;
                const int m = mt * 16 + hi4 * 4 + q;
                const int o = swz(m, n);
                lds[stO + o] = vh;
                lds[stO + 8192 + o] = (_Float16)(v - (float)vh);
            }
        }
    }
    // my state writes done -> raw barrier (DMA vmcnt stays live across it)
    asm volatile("s_waitcnt lgkmcnt(0)" ::: "memory");
    __builtin_amdgcn_s_barrier();
    SBAR;
}

__global__ __launch_bounds__(512, 2) void ms1_main(
    const float* __restrict__ Y0,
    const float* __restrict__ bvec,
    const _Float16* __restrict__ B1h, const _Float16* __restrict__ B2h,
    float* __restrict__ out)
{
    extern __shared__ _Float16 lds[];   // 66560 halfs = 133120 B

    const int tid  = threadIdx.x;
    const int lane = tid & 63, w = tid >> 6;   // 8 waves; wave w: cols 32w..+31
    const int l15 = lane & 15, hi4 = lane >> 4;
    const size_t row0 = (size_t)blockIdx.x * 32;

    // B fragment offsets within a buffer (halfs)
    const int bfw = w << 10;                       // wave region base
    const int c0 = l15, c1 = 16 + l15;             // c_local of the 2 n-tiles
    const int bf0 = (c0 * 4 + (hi4 ^ ((c0 >> 1) & 3))) * 8;
    const int bf1 = (c1 * 4 + (hi4 ^ ((c1 >> 1) & 3))) * 8;
    // DMA geometry (halfs): per-lane source, wave-uniform dest
    const int gsrc = (w << 10) + lane * 8;
    const int gdst = (w << 10);
    const size_t bsrc = (size_t)((w << 5) + (lane & 31)) * 64;  // bias gather

    float Ym[2][2][4], Zm[2][2][4];   // fp32 masters [mt][nt][q]

#pragma unroll
    for (int mt = 0; mt < 2; ++mt) {
#pragma unroll
        for (int nt = 0; nt < 2; ++nt) {
            const int n = (w << 5) + nt * 16 + l15;
#pragma unroll
            for (int q = 0; q < 4; ++q) {
                const int m = mt * 16 + hi4 * 4 + q;
                const size_t base = (row0 + m) * 512;
                const float y = Y0[base + n];
                const float z = Y0[base + 256 + n];
                Ym[mt][nt][q] = y; Zm[mt][nt][q] = z;
                const _Float16 yh = (_Float16)y;
                const int o = swz(m, n);
                lds[ST_Y + o] = yh;
                lds[ST_Y + 8192 + o] = (_Float16)(y - (float)yh);
            }
        }
    }
    __syncthreads();   // init handoff (no DMAs in flight yet)

    // prologue: DMA tiles 0..3 of (j=0, B1) into bufs 0..3 (8 ops in flight)
#pragma unroll
    for (int t0 = 0; t0 < 4; ++t0) {
        _Float16* db = lds + BUF0 + t0 * 8192 + gdst;
        gload16(B1h + t0 * 8192 + gsrc,       db);
        gload16(B1h + t0 * 8192 + gsrc + 512, db + 512);
    }

    for (int j = 0; j < 64; ++j) {
        const _Float16* C1 = B1h + (size_t)j * 65536;
        const _Float16* C2 = B2h + (size_t)j * 65536;
        const int jn = (j < 63) ? j + 1 : 0;   // wrap: dead prefetch, in-bounds
        // Z += H*tanh(Y @ K^T + b[256:])   (A=Y; next B = B2 of same j)
        phase<false>(lds, ST_Y, ST_Z, C1, C2, bvec + 256 * 64 + j, Zm,
                     w, l15, hi4, bfw, bf0, bf1, gsrc, gdst, bsrc);
        // Y += H*tanh(b[:256] - Z @ K)     (A=Z; next B = B1 of j+1)
        phase<true>(lds, ST_Z, ST_Y, C2, B1h + (size_t)jn * 65536,
                    bvec + j, Ym,
                    w, l15, hi4, bfw, bf0, bf1, gsrc, gdst, bsrc);
    }

#pragma unroll
    for (int mt = 0; mt < 2; ++mt) {
#pragma unroll
        for (int nt = 0; nt < 2; ++nt) {
            const int n = (w << 5) + nt * 16 + l15;
#pragma unroll
            for (int q = 0; q < 4; ++q) {
                const int m = mt * 16 + hi4 * 4 + q;
                const size_t base = (row0 + m) * 512;
                out[base + n]       = Ym[mt][nt][q];
                out[base + 256 + n] = Zm[mt][nt][q];
            }
        }
    }
}

extern "C" void kernel_launch(void* const* d_in, const int* in_sizes, int n_in,
                              void* d_out, int out_size, void* d_ws, size_t ws_size,
                              hipStream_t stream) {
    (void)in_sizes; (void)n_in; (void)out_size;
    const float* Y0 = (const float*)d_in[0];
    const float* K  = (const float*)d_in[1];
    const float* b  = (const float*)d_in[2];

    const size_t ARR = (size_t)64 * 256 * 256;   // halfs per array
    if (ws_size < 2 * ARR * sizeof(_Float16)) return;

    _Float16* B1h = (_Float16*)d_ws;
    _Float16* B2h = B1h + ARR;

    hipFuncSetAttribute((const void*)ms1_main,
                        hipFuncAttributeMaxDynamicSharedMemorySize, 133120);

    prep_split<<<512, 256, 0, stream>>>(K, B1h, B2h);
    ms1_main<<<256, 512, 133120, stream>>>(Y0, b, B1h, B2h, (float*)d_out);
}

// Round 10
// 287.103 us; speedup vs baseline: 3.5836x; 1.3246x over previous
//
#include <hip/hip_runtime.h>

// MS1: 64-layer reversible net, fused single-kernel recurrence.
//   Z += H*tanh(Y @ K_j^T + b_j[256:]);  Y += H*tanh(b_j[:256] - Z @ K_j)
// R10 = R9 with the A-lo Ozaki term dropped: pure fp16 GEMM inputs, fp32
// master state in registers (error analysis: B-fp16 drop in R9 changed
// absmax by 0; A contributes the same magnitude -> ~0.03 vs 0.1037 thr).
// Halves A LDS reads (the R9 bottleneck), halves state LDS, 4 MFMAs/kt.
// Structure unchanged: 512 thr (8 waves), wave w owns cols 32w..32w+31 x
// both m-tiles; B staged wave-locally via global_load_lds into 4 rotating
// 16KB buffers with exact counted vmcnt; one raw s_barrier per phase.

typedef _Float16 f16x8 __attribute__((ext_vector_type(8)));
typedef _Float16 f16x2 __attribute__((ext_vector_type(2)));
typedef float    f32x4 __attribute__((ext_vector_type(4)));

#define H_STEP 0.015625f   // 1/64

// LDS layout in halfs:
#define ST_Y   0          // Y hi: 0..8191
#define ST_Z   8192       // Z hi
#define BUF0   16384      // 4 buffers x 8192 halfs (16KB each)
#define BIASO  49152      // 8 waves x 64 f32 = 1024 halfs
// total 50176 halfs = 100352 bytes

__device__ __forceinline__ float fast_tanh(float x) {
    float xc = fminf(fmaxf(x, -9.0f), 9.0f);
    float t  = __builtin_amdgcn_exp2f(xc * 2.8853900817779268f); // 2x*log2(e)
    return (t - 1.0f) * __builtin_amdgcn_rcpf(t + 1.0f);
}

// state LDS index with XOR swizzle (16B-granular column rotation per row)
__device__ __forceinline__ int swz(int m, int k) {
    return (m << 8) + (k ^ ((m & 7) << 3));
}

__device__ __forceinline__ void gload16(const _Float16* g, _Float16* l) {
    __builtin_amdgcn_global_load_lds(
        (const __attribute__((address_space(1))) unsigned int*)g,
        (__attribute__((address_space(3))) unsigned int*)l, 16, 0, 0);
}
__device__ __forceinline__ void gload4(const float* g, _Float16* l) {
    __builtin_amdgcn_global_load_lds(
        (const __attribute__((address_space(1))) unsigned int*)g,
        (__attribute__((address_space(3))) unsigned int*)l, 4, 0, 0);
}

// ---------------- prep: K[a][b][j] -> DMA-tile-ordered fp16 arrays ----------
// Layout: [j][kt][w 0..7][u 0..127][8 halfs]; unit u = c_local*4 + (chunk ^
// ((c_local>>1)&3)) holds B[col=32w+c_local][k=kt*32+chunk*8 ..+8].
// B1[n][k]=K[n][k][j] (Y@K^T);  B2[n][k]=K[k][n][j] (Z@K)
__global__ __launch_bounds__(256) void prep_split(
    const float* __restrict__ K,
    _Float16* __restrict__ B1h, _Float16* __restrict__ B2h)
{
    __shared__ float tile[32][33][9];
    const int a0 = (blockIdx.x & 7) << 5;
    const int b0 = ((blockIdx.x >> 3) & 7) << 5;
    const int j0 = (blockIdx.x >> 6) << 3;
    const int t = threadIdx.x;

    for (int idx = t; idx < 8192; idx += 256) {
        const int jj = idx & 7, bb = (idx >> 3) & 31, aa = idx >> 8;
        tile[aa][bb][jj] = K[((size_t)(a0 + aa) * 256 + (b0 + bb)) * 64 + (j0 + jj)];
    }
    __syncthreads();

    // B1: n = a0+aa (w1=a0>>5, c_local=aa), k = b0+kl (kt=b0>>5)
    {
        const int w1 = a0 >> 5, kt = b0 >> 5;
        for (int idx = t; idx < 4096; idx += 256) {
            const int p = idx & 15, aa = (idx >> 4) & 31, jj = idx >> 9;
            const int kl = 2 * p, c = kl >> 3, e = kl & 7;
            const int u = aa * 4 + (c ^ ((aa >> 1) & 3));
            const size_t off = ((size_t)((j0 + jj) * 8 + kt)) * 8192 + w1 * 1024 + u * 8 + e;
            const f16x2 hv = {(_Float16)tile[aa][kl][jj], (_Float16)tile[aa][kl + 1][jj]};
            *(f16x2*)(B1h + off) = hv;
        }
    }
    // B2: n = b0+bb (w2=b0>>5, c_local=bb), k = a0+kl (kt=a0>>5)
    {
        const int w2 = b0 >> 5, kt = a0 >> 5;
        for (int idx = t; idx < 4096; idx += 256) {
            const int p = idx & 15, bb = (idx >> 4) & 31, jj = idx >> 9;
            const int kl = 2 * p, c = kl >> 3, e = kl & 7;
            const int u = bb * 4 + (c ^ ((bb >> 1) & 3));
            const size_t off = ((size_t)((j0 + jj) * 8 + kt)) * 8192 + w2 * 1024 + u * 8 + e;
            const f16x2 hv = {(_Float16)tile[kl][bb][jj], (_Float16)tile[kl + 1][bb][jj]};
            *(f16x2*)(B2h + off) = hv;
        }
    }
}

#define MFMA16(A, B, C) __builtin_amdgcn_mfma_f32_16x16x32_f16((A), (B), (C), 0, 0, 0)
#define SBAR __builtin_amdgcn_sched_barrier(0)

// issue the 4 ds_reads for k-tile PK into the given regs
#define LOAD_FRAGS(AH0, AH1, BH0, BH1, PK)                                      \
    {                                                                           \
        const int k0_ = (PK) * 32 + hi4 * 8;                                    \
        const _Float16* bb_ = lds + BUF0 + ((PK) & 3) * 8192 + bfw;             \
        BH0 = *(const f16x8*)(bb_ + bf0);                                       \
        BH1 = *(const f16x8*)(bb_ + bf1);                                       \
        AH0 = *(const f16x8*)(lds + stA + swz(l15, k0_));                       \
        AH1 = *(const f16x8*)(lds + stA + swz(16 + l15, k0_));                  \
    }

// one k-tile. VM = exact vmcnt so tile VKT+1 is fully in LDS before its reads.
// Order: [vmcnt][lgkm0: my kt-reads done, buf VKT&3 free][DMA T_{VKT+4} into
// buf VKT&3][issue reads R_{VKT+1}][4 MFMAs on CUR regs].
#define KT(VKT, VM, CAH0,CAH1,CBH0,CBH1, NAH0,NAH1,NBH0,NBH1)                   \
    {                                                                           \
        if ((VKT) < 7) { asm volatile("s_waitcnt vmcnt(" #VM ")" ::: "memory"); SBAR; } \
        asm volatile("s_waitcnt lgkmcnt(0)" ::: "memory"); SBAR;                \
        {                                                                       \
            const _Float16* sb_ = ((VKT) < 4) ? Bc : Bn;                        \
            const int tt_ = ((VKT) + 4) & 7;                                    \
            _Float16* db_ = lds + BUF0 + ((VKT) & 3) * 8192 + gdst;             \
            gload16(sb_ + tt_ * 8192 + gsrc,       db_);                        \
            gload16(sb_ + tt_ * 8192 + gsrc + 512, db_ + 512);                  \
        }                                                                       \
        if ((VKT) == 0) gload4(biasG + bsrc, lds + BIASO + (w << 7));           \
        if ((VKT) < 7) LOAD_FRAGS(NAH0, NAH1, NBH0, NBH1, (VKT) + 1)            \
        accH00 = MFMA16(CAH0, CBH0, accH00);                                    \
        accH01 = MFMA16(CAH0, CBH1, accH01);                                    \
        accH10 = MFMA16(CAH1, CBH0, accH10);                                    \
        accH11 = MFMA16(CAH1, CBH1, accH11);                                    \
    }

// one half-layer: 8 pipelined k-tiles + epilogue + single raw barrier
template<bool NEG>
__device__ __forceinline__ void phase(
    _Float16* lds, const int stA, const int stO,
    const _Float16* __restrict__ Bc,   // this half-layer's B array (j base)
    const _Float16* __restrict__ Bn,   // next half-layer's B array
    const float* __restrict__ biasG,   // bvec + featbase*64 + j
    float (&M)[2][2][4],
    const int w, const int l15, const int hi4,
    const int bfw, const int bf0, const int bf1,
    const int gsrc, const int gdst, const size_t bsrc)
{
    f32x4 accH00 = {0.f,0.f,0.f,0.f}, accH01 = {0.f,0.f,0.f,0.f};
    f32x4 accH10 = {0.f,0.f,0.f,0.f}, accH11 = {0.f,0.f,0.f,0.f};

    f16x8 cah0, cah1, cbh0, cbh1;
    f16x8 nah0, nah1, nbh0, nbh1;

    // pre-loop: T0 resident (outstanding T1,T2,T3 = 6), read k-tile 0
    asm volatile("s_waitcnt vmcnt(6)" ::: "memory"); SBAR;
    LOAD_FRAGS(cah0, cah1, cbh0, cbh1, 0)

    KT(0, 4, cah0,cah1,cbh0,cbh1, nah0,nah1,nbh0,nbh1)
    KT(1, 5, nah0,nah1,nbh0,nbh1, cah0,cah1,cbh0,cbh1)
    KT(2, 5, cah0,cah1,cbh0,cbh1, nah0,nah1,nbh0,nbh1)
    KT(3, 5, nah0,nah1,nbh0,nbh1, cah0,cah1,cbh0,cbh1)
    KT(4, 4, cah0,cah1,cbh0,cbh1, nah0,nah1,nbh0,nbh1)
    KT(5, 4, nah0,nah1,nbh0,nbh1, cah0,cah1,cbh0,cbh1)
    KT(6, 4, cah0,cah1,cbh0,cbh1, nah0,nah1,nbh0,nbh1)
    KT(7, 0, nah0,nah1,nbh0,nbh1, cah0,cah1,cbh0,cbh1)

    // epilogue: bias from LDS, master += H*tanh(bias +/- acc), state hi to LDS
    const float* bp = (const float*)(lds + BIASO + (w << 7));
    const float bv0 = bp[l15], bv1 = bp[l15 + 16];

#pragma unroll
    for (int mt = 0; mt < 2; ++mt) {
#pragma unroll
        for (int nt = 0; nt < 2; ++nt) {
            const f32x4 s4 = (mt == 0) ? ((nt == 0) ? accH00 : accH01)
                                       : ((nt == 0) ? accH10 : accH11);
            const float bv = nt ? bv1 : bv0;
            const int n = (w << 5) + nt * 16 + l15;
#pragma unroll
            for (int q = 0; q < 4; ++q) {
                const float x = NEG ? (bv - s4[q]) : (s4[q] + bv);
                const float v = M[mt][nt][q] + H_STEP * fast_tanh(x);
                M[mt][nt][q] = v;
                const int m = mt * 16 + hi4 * 4 + q;
                lds[stO + swz(m, n)] = (_Float16)v;
            }
        }
    }
    // my state writes done -> raw barrier (DMA vmcnt stays live across it)
    asm volatile("s_waitcnt lgkmcnt(0)" ::: "memory");
    __builtin_amdgcn_s_barrier();
    SBAR;
}

__global__ __launch_bounds__(512, 2) void ms1_main(
    const float* __restrict__ Y0,
    const float* __restrict__ bvec,
    const _Float16* __restrict__ B1h, const _Float16* __restrict__ B2h,
    float* __restrict__ out)
{
    extern __shared__ _Float16 lds[];   // 50176 halfs = 100352 B

    const int tid  = threadIdx.x;
    const int lane = tid & 63, w = tid >> 6;   // 8 waves; wave w: cols 32w..+31
    const int l15 = lane & 15, hi4 = lane >> 4;
    const size_t row0 = (size_t)blockIdx.x * 32;

    // B fragment offsets within a buffer (halfs)
    const int bfw = w << 10;                       // wave region base
    const int c0 = l15, c1 = 16 + l15;             // c_local of the 2 n-tiles
    const int bf0 = (c0 * 4 + (hi4 ^ ((c0 >> 1) & 3))) * 8;
    const int bf1 = (c1 * 4 + (hi4 ^ ((c1 >> 1) & 3))) * 8;
    // DMA geometry (halfs): per-lane source, wave-uniform dest
    const int gsrc = (w << 10) + lane * 8;
    const int gdst = (w << 10);
    const size_t bsrc = (size_t)((w << 5) + (lane & 31)) * 64;  // bias gather

    float Ym[2][2][4], Zm[2][2][4];   // fp32 masters [mt][nt][q]

#pragma unroll
    for (int mt = 0; mt < 2; ++mt) {
#pragma unroll
        for (int nt = 0; nt < 2; ++nt) {
            const int n = (w << 5) + nt * 16 + l15;
#pragma unroll
            for (int q = 0; q < 4; ++q) {
                const int m = mt * 16 + hi4 * 4 + q;
                const size_t base = (row0 + m) * 512;
                const float y = Y0[base + n];
                const float z = Y0[base + 256 + n];
                Ym[mt][nt][q] = y; Zm[mt][nt][q] = z;
                lds[ST_Y + swz(m, n)] = (_Float16)y;
            }
        }
    }
    __syncthreads();   // init handoff (no DMAs in flight yet)

    // prologue: DMA tiles 0..3 of (j=0, B1) into bufs 0..3 (8 ops in flight)
#pragma unroll
    for (int t0 = 0; t0 < 4; ++t0) {
        _Float16* db = lds + BUF0 + t0 * 8192 + gdst;
        gload16(B1h + t0 * 8192 + gsrc,       db);
        gload16(B1h + t0 * 8192 + gsrc + 512, db + 512);
    }

    for (int j = 0; j < 64; ++j) {
        const _Float16* C1 = B1h + (size_t)j * 65536;
        const _Float16* C2 = B2h + (size_t)j * 65536;
        const int jn = (j < 63) ? j + 1 : 0;   // wrap: dead prefetch, in-bounds
        // Z += H*tanh(Y @ K^T + b[256:])   (A=Y; next B = B2 of same j)
        phase<false>(lds, ST_Y, ST_Z, C1, C2, bvec + 256 * 64 + j, Zm,
                     w, l15, hi4, bfw, bf0, bf1, gsrc, gdst, bsrc);
        // Y += H*tanh(b[:256] - Z @ K)     (A=Z; next B = B1 of j+1)
        phase<true>(lds, ST_Z, ST_Y, C2, B1h + (size_t)jn * 65536,
                    bvec + j, Ym,
                    w, l15, hi4, bfw, bf0, bf1, gsrc, gdst, bsrc);
    }

#pragma unroll
    for (int mt = 0; mt < 2; ++mt) {
#pragma unroll
        for (int nt = 0; nt < 2; ++nt) {
            const int n = (w << 5) + nt * 16 + l15;
#pragma unroll
            for (int q = 0; q < 4; ++q) {
                const int m = mt * 16 + hi4 * 4 + q;
                const size_t base = (row0 + m) * 512;
                out[base + n]       = Ym[mt][nt][q];
                out[base + 256 + n] = Zm[mt][nt][q];
            }
        }
    }
}

extern "C" void kernel_launch(void* const* d_in, const int* in_sizes, int n_in,
                              void* d_out, int out_size, void* d_ws, size_t ws_size,
                              hipStream_t stream) {
    (void)in_sizes; (void)n_in; (void)out_size;
    const float* Y0 = (const float*)d_in[0];
    const float* K  = (const float*)d_in[1];
    const float* b  = (const float*)d_in[2];

    const size_t ARR = (size_t)64 * 256 * 256;   // halfs per array
    if (ws_size < 2 * ARR * sizeof(_Float16)) return;

    _Float16* B1h = (_Float16*)d_ws;
    _Float16* B2h = B1h + ARR;

    hipFuncSetAttribute((const void*)ms1_main,
                        hipFuncAttributeMaxDynamicSharedMemorySize, 100352);

    prep_split<<<512, 256, 0, stream>>>(K, B1h, B2h);
    ms1_main<<<256, 512, 100352, stream>>>(Y0, b, B1h, B2h, (float*)d_out);
}

// Round 11
// 283.148 us; speedup vs baseline: 3.6337x; 1.0140x over previous
//
#include <hip/hip_runtime.h>

// MS1: 64-layer reversible net, fused single-kernel recurrence.
//   Z += H*tanh(Y @ K_j^T + b_j[256:]);  Y += H*tanh(b_j[:256] - Z @ K_j)
// R11 = R10 + 2-deep ds_read fragment pipeline: 3 rotating register sets
// (S0/S1/S2); frags for kt v issue at KT(v-2) (~250cyc cover vs ~40 in R10);
// counted lgkmcnt(4) waits. Ledger: steady vmcnt(2) (bias shifts KT1 to 3),
// DMA tile T+4 -> buf T&3 (freed by the lgkm wait), taper KT6/7, 8 DMA ops
// in flight across the phase barrier, pre-wait vmcnt(4).
// Structure else unchanged from R10: 512 thr (8 waves), wave w owns cols
// 32w..32w+31 x both m-tiles; fp16 GEMM inputs, fp32 masters in registers;
// B staged wave-locally via global_load_lds into 4 rotating 16KB buffers;
// one raw s_barrier per phase. LDS 100352 B.

typedef _Float16 f16x8 __attribute__((ext_vector_type(8)));
typedef _Float16 f16x2 __attribute__((ext_vector_type(2)));
typedef float    f32x4 __attribute__((ext_vector_type(4)));

#define H_STEP 0.015625f   // 1/64

// LDS layout in halfs:
#define ST_Y   0          // Y hi: 0..8191
#define ST_Z   8192       // Z hi
#define BUF0   16384      // 4 buffers x 8192 halfs (16KB each)
#define BIASO  49152      // 8 waves x 64 f32 = 1024 halfs
// total 50176 halfs = 100352 bytes

__device__ __forceinline__ float fast_tanh(float x) {
    float xc = fminf(fmaxf(x, -9.0f), 9.0f);
    float t  = __builtin_amdgcn_exp2f(xc * 2.8853900817779268f); // 2x*log2(e)
    return (t - 1.0f) * __builtin_amdgcn_rcpf(t + 1.0f);
}

// state LDS index with XOR swizzle (16B-granular column rotation per row)
__device__ __forceinline__ int swz(int m, int k) {
    return (m << 8) + (k ^ ((m & 7) << 3));
}

__device__ __forceinline__ void gload16(const _Float16* g, _Float16* l) {
    __builtin_amdgcn_global_load_lds(
        (const __attribute__((address_space(1))) unsigned int*)g,
        (__attribute__((address_space(3))) unsigned int*)l, 16, 0, 0);
}
__device__ __forceinline__ void gload4(const float* g, _Float16* l) {
    __builtin_amdgcn_global_load_lds(
        (const __attribute__((address_space(1))) unsigned int*)g,
        (__attribute__((address_space(3))) unsigned int*)l, 4, 0, 0);
}

// ---------------- prep: K[a][b][j] -> DMA-tile-ordered fp16 arrays ----------
// Layout: [j][kt][w 0..7][u 0..127][8 halfs]; unit u = c_local*4 + (chunk ^
// ((c_local>>1)&3)) holds B[col=32w+c_local][k=kt*32+chunk*8 ..+8].
// B1[n][k]=K[n][k][j] (Y@K^T);  B2[n][k]=K[k][n][j] (Z@K)
__global__ __launch_bounds__(256) void prep_split(
    const float* __restrict__ K,
    _Float16* __restrict__ B1h, _Float16* __restrict__ B2h)
{
    __shared__ float tile[32][33][9];
    const int a0 = (blockIdx.x & 7) << 5;
    const int b0 = ((blockIdx.x >> 3) & 7) << 5;
    const int j0 = (blockIdx.x >> 6) << 3;
    const int t = threadIdx.x;

    for (int idx = t; idx < 8192; idx += 256) {
        const int jj = idx & 7, bb = (idx >> 3) & 31, aa = idx >> 8;
        tile[aa][bb][jj] = K[((size_t)(a0 + aa) * 256 + (b0 + bb)) * 64 + (j0 + jj)];
    }
    __syncthreads();

    {
        const int w1 = a0 >> 5, kt = b0 >> 5;
        for (int idx = t; idx < 4096; idx += 256) {
            const int p = idx & 15, aa = (idx >> 4) & 31, jj = idx >> 9;
            const int kl = 2 * p, c = kl >> 3, e = kl & 7;
            const int u = aa * 4 + (c ^ ((aa >> 1) & 3));
            const size_t off = ((size_t)((j0 + jj) * 8 + kt)) * 8192 + w1 * 1024 + u * 8 + e;
            const f16x2 hv = {(_Float16)tile[aa][kl][jj], (_Float16)tile[aa][kl + 1][jj]};
            *(f16x2*)(B1h + off) = hv;
        }
    }
    {
        const int w2 = b0 >> 5, kt = a0 >> 5;
        for (int idx = t; idx < 4096; idx += 256) {
            const int p = idx & 15, bb = (idx >> 4) & 31, jj = idx >> 9;
            const int kl = 2 * p, c = kl >> 3, e = kl & 7;
            const int u = bb * 4 + (c ^ ((bb >> 1) & 3));
            const size_t off = ((size_t)((j0 + jj) * 8 + kt)) * 8192 + w2 * 1024 + u * 8 + e;
            const f16x2 hv = {(_Float16)tile[kl][bb][jj], (_Float16)tile[kl + 1][bb][jj]};
            *(f16x2*)(B2h + off) = hv;
        }
    }
}

#define MFMA16(A, B, C) __builtin_amdgcn_mfma_f32_16x16x32_f16((A), (B), (C), 0, 0, 0)
#define SBAR __builtin_amdgcn_sched_barrier(0)
#define WAITV(N) { asm volatile("s_waitcnt vmcnt(" #N ")" ::: "memory"); SBAR; }
#define WAITL(N) { asm volatile("s_waitcnt lgkmcnt(" #N ")" ::: "memory"); SBAR; }

// issue the 4 ds_reads for k-tile PK into a register set
#define LOADF(A0, A1, B0, B1, PK)                                               \
    {                                                                           \
        const int k0_ = (PK) * 32 + hi4 * 8;                                    \
        const _Float16* bb_ = lds + BUF0 + ((PK) & 3) * 8192 + bfw;             \
        B0 = *(const f16x8*)(bb_ + bf0);                                        \
        B1 = *(const f16x8*)(bb_ + bf1);                                        \
        A0 = *(const f16x8*)(lds + stA + swz(l15, k0_));                        \
        A1 = *(const f16x8*)(lds + stA + swz(16 + l15, k0_));                   \
    }

// DMA tile T (0..11; >=8 -> next phase's tile T-8) into buf T&3
#define DMAT(T)                                                                 \
    {                                                                           \
        const _Float16* sb_ = ((T) < 8) ? Bc : Bn;                              \
        _Float16* db_ = lds + BUF0 + ((T) & 3) * 8192 + gdst;                   \
        gload16(sb_ + ((T) & 7) * 8192 + gsrc,       db_);                      \
        gload16(sb_ + ((T) & 7) * 8192 + gsrc + 512, db_ + 512);                \
    }

#define FMAS(A0, A1, B0, B1)                                                    \
    accH00 = MFMA16(A0, B0, accH00);                                            \
    accH01 = MFMA16(A0, B1, accH01);                                            \
    accH10 = MFMA16(A1, B0, accH10);                                            \
    accH11 = MFMA16(A1, B1, accH11);

// one half-layer: 8 k-tiles, 2-deep read pipeline + epilogue + raw barrier
template<bool NEG>
__device__ __forceinline__ void phase(
    _Float16* lds, const int stA, const int stO,
    const _Float16* __restrict__ Bc,   // this half-layer's B array (j base)
    const _Float16* __restrict__ Bn,   // next half-layer's B array
    const float* __restrict__ biasG,   // bvec + featbase*64 + j
    float (&M)[2][2][4],
    const int w, const int l15, const int hi4,
    const int bfw, const int bf0, const int bf1,
    const int gsrc, const int gdst, const size_t bsrc)
{
    f32x4 accH00 = {0.f,0.f,0.f,0.f}, accH01 = {0.f,0.f,0.f,0.f};
    f32x4 accH10 = {0.f,0.f,0.f,0.f}, accH11 = {0.f,0.f,0.f,0.f};

    f16x8 a00,a01,b00,b01;   // S0
    f16x8 a10,a11,b10,b11;   // S1
    f16x8 a20,a21,b20,b21;   // S2

    // entry: 8 DMA ops outstanding (this phase t2,t3 + taper t0,t1 already
    // retired pattern) -> wait to 4: tiles 0,1 resident
    WAITV(4)
    LOADF(a00,a01,b00,b01, 0)
    LOADF(a10,a11,b10,b11, 1)

    // KT0
    WAITV(2) WAITL(4)
    gload4(biasG + bsrc, lds + BIASO + (w << 7));
    DMAT(4)  LOADF(a20,a21,b20,b21, 2)  FMAS(a00,a01,b00,b01)
    // KT1
    WAITV(3) WAITL(4)
    DMAT(5)  LOADF(a00,a01,b00,b01, 3)  FMAS(a10,a11,b10,b11)
    // KT2
    WAITV(2) WAITL(4)
    DMAT(6)  LOADF(a10,a11,b10,b11, 4)  FMAS(a20,a21,b20,b21)
    // KT3
    WAITV(2) WAITL(4)
    DMAT(7)  LOADF(a20,a21,b20,b21, 5)  FMAS(a00,a01,b00,b01)
    // KT4
    WAITV(2) WAITL(4)
    DMAT(8)  LOADF(a00,a01,b00,b01, 6)  FMAS(a10,a11,b10,b11)
    // KT5
    WAITV(2) WAITL(4)
    DMAT(9)  LOADF(a10,a11,b10,b11, 7)  FMAS(a20,a21,b20,b21)
    // KT6 (taper: no new reads)
    WAITL(4)
    DMAT(10) FMAS(a00,a01,b00,b01)
    // KT7
    WAITL(0)
    DMAT(11) FMAS(a10,a11,b10,b11)

    // epilogue: bias from LDS, master += H*tanh(bias +/- acc), state hi to LDS
    const float* bp = (const float*)(lds + BIASO + (w << 7));
    const float bv0 = bp[l15], bv1 = bp[l15 + 16];

#pragma unroll
    for (int mt = 0; mt < 2; ++mt) {
#pragma unroll
        for (int nt = 0; nt < 2; ++nt) {
            const f32x4 s4 = (mt == 0) ? ((nt == 0) ? accH00 : accH01)
                                       : ((nt == 0) ? accH10 : accH11);
            const float bv = nt ? bv1 : bv0;
            const int n = (w << 5) + nt * 16 + l15;
#pragma unroll
            for (int q = 0; q < 4; ++q) {
                const float x = NEG ? (bv - s4[q]) : (s4[q] + bv);
                const float v = M[mt][nt][q] + H_STEP * fast_tanh(x);
                M[mt][nt][q] = v;
                const int m = mt * 16 + hi4 * 4 + q;
                lds[stO + swz(m, n)] = (_Float16)v;
            }
        }
    }
    // my state writes done -> raw barrier (DMA vmcnt stays live across it)
    asm volatile("s_waitcnt lgkmcnt(0)" ::: "memory");
    __builtin_amdgcn_s_barrier();
    SBAR;
}

__global__ __launch_bounds__(512, 2) void ms1_main(
    const float* __restrict__ Y0,
    const float* __restrict__ bvec,
    const _Float16* __restrict__ B1h, const _Float16* __restrict__ B2h,
    float* __restrict__ out)
{
    extern __shared__ _Float16 lds[];   // 50176 halfs = 100352 B

    const int tid  = threadIdx.x;
    const int lane = tid & 63, w = tid >> 6;   // 8 waves; wave w: cols 32w..+31
    const int l15 = lane & 15, hi4 = lane >> 4;
    const size_t row0 = (size_t)blockIdx.x * 32;

    const int bfw = w << 10;
    const int c0 = l15, c1 = 16 + l15;
    const int bf0 = (c0 * 4 + (hi4 ^ ((c0 >> 1) & 3))) * 8;
    const int bf1 = (c1 * 4 + (hi4 ^ ((c1 >> 1) & 3))) * 8;
    const int gsrc = (w << 10) + lane * 8;
    const int gdst = (w << 10);
    const size_t bsrc = (size_t)((w << 5) + (lane & 31)) * 64;  // bias gather

    float Ym[2][2][4], Zm[2][2][4];   // fp32 masters [mt][nt][q]

#pragma unroll
    for (int mt = 0; mt < 2; ++mt) {
#pragma unroll
        for (int nt = 0; nt < 2; ++nt) {
            const int n = (w << 5) + nt * 16 + l15;
#pragma unroll
            for (int q = 0; q < 4; ++q) {
                const int m = mt * 16 + hi4 * 4 + q;
                const size_t base = (row0 + m) * 512;
                const float y = Y0[base + n];
                const float z = Y0[base + 256 + n];
                Ym[mt][nt][q] = y; Zm[mt][nt][q] = z;
                lds[ST_Y + swz(m, n)] = (_Float16)y;
            }
        }
    }
    __syncthreads();   // init handoff (no DMAs in flight yet)

    // prologue: DMA tiles 0..3 of (j=0, B1) into bufs 0..3 (8 ops in flight)
#pragma unroll
    for (int t0 = 0; t0 < 4; ++t0) {
        _Float16* db = lds + BUF0 + t0 * 8192 + gdst;
        gload16(B1h + t0 * 8192 + gsrc,       db);
        gload16(B1h + t0 * 8192 + gsrc + 512, db + 512);
    }

    for (int j = 0; j < 64; ++j) {
        const _Float16* C1 = B1h + (size_t)j * 65536;
        const _Float16* C2 = B2h + (size_t)j * 65536;
        const int jn = (j < 63) ? j + 1 : 0;   // wrap: dead prefetch, in-bounds
        // Z += H*tanh(Y @ K^T + b[256:])   (A=Y; next B = B2 of same j)
        phase<false>(lds, ST_Y, ST_Z, C1, C2, bvec + 256 * 64 + j, Zm,
                     w, l15, hi4, bfw, bf0, bf1, gsrc, gdst, bsrc);
        // Y += H*tanh(b[:256] - Z @ K)     (A=Z; next B = B1 of j+1)
        phase<true>(lds, ST_Z, ST_Y, C2, B1h + (size_t)jn * 65536,
                    bvec + j, Ym,
                    w, l15, hi4, bfw, bf0, bf1, gsrc, gdst, bsrc);
    }

#pragma unroll
    for (int mt = 0; mt < 2; ++mt) {
#pragma unroll
        for (int nt = 0; nt < 2; ++nt) {
            const int n = (w << 5) + nt * 16 + l15;
#pragma unroll
            for (int q = 0; q < 4; ++q) {
                const int m = mt * 16 + hi4 * 4 + q;
                const size_t base = (row0 + m) * 512;
                out[base + n]       = Ym[mt][nt][q];
                out[base + 256 + n] = Zm[mt][nt][q];
            }
        }
    }
}

extern "C" void kernel_launch(void* const* d_in, const int* in_sizes, int n_in,
                              void* d_out, int out_size, void* d_ws, size_t ws_size,
                              hipStream_t stream) {
    (void)in_sizes; (void)n_in; (void)out_size;
    const float* Y0 = (const float*)d_in[0];
    const float* K  = (const float*)d_in[1];
    const float* b  = (const float*)d_in[2];

    const size_t ARR = (size_t)64 * 256 * 256;   // halfs per array
    if (ws_size < 2 * ARR * sizeof(_Float16)) return;

    _Float16* B1h = (_Float16*)d_ws;
    _Float16* B2h = B1h + ARR;

    hipFuncSetAttribute((const void*)ms1_main,
                        hipFuncAttributeMaxDynamicSharedMemorySize, 100352);

    prep_split<<<512, 256, 0, stream>>>(K, B1h, B2h);
    ms1_main<<<256, 512, 100352, stream>>>(Y0, b, B1h, B2h, (float*)d_out);
}